// Round 4
// baseline (167.052 us; speedup 1.0000x reference)
//
#include <hip/hip_runtime.h>
#include <hip/hip_bf16.h>
#include <math.h>

#define LTOK 512
#define DDIM 512
#define NEXP 32
#define HDIM 512

typedef __attribute__((ext_vector_type(8))) short short8;
typedef __attribute__((ext_vector_type(4))) float floatx4;

// round-to-nearest-even fp32->bf16, packed pair: low16 = rne(a), high16 = rne(b)
__device__ __forceinline__ unsigned bpack(float a, float b) {
    unsigned ua = __float_as_uint(a), ub = __float_as_uint(b);
    ua += 0x7FFFu + ((ua >> 16) & 1u);
    ub += 0x7FFFu + ((ub >> 16) & 1u);
    return (ua >> 16) | (ub & 0xFFFF0000u);
}

// ws layout (bytes):
//   [0,128)             cnt: 32 ints
//   [256, +64K)         alist: 32*512 ints  (assignment id = 2*token+k)
//   [65792, +64K)       slist: 32*512 floats (routing weight * per_expert_scale)
//   [131328, +512K)     xb: 512x512 bf16 (x rounded to bf16)
//   [655616, +1M)       act: 1024x512 bf16
//   [1704192, +2M)      yb: 1024x512 fp32 (per-assignment scaled expert output)
// total ~3.7 MB

__global__ __launch_bounds__(64) void router_kernel(
    const float* __restrict__ x, const float* __restrict__ rs,
    const float* __restrict__ Wr, const float* __restrict__ pes,
    int* __restrict__ cnt, int* __restrict__ alist, float* __restrict__ slist,
    short* __restrict__ xb)
{
    const int t = blockIdx.x;
    const int lane = threadIdx.x;

    float xv[8];
    float ss = 0.f;
#pragma unroll
    for (int j = 0; j < 8; ++j) {
        xv[j] = x[t * DDIM + j * 64 + lane];
        ss += xv[j] * xv[j];
    }
    // emit bf16 copy of x for the expert GEMMs
#pragma unroll
    for (int j = 0; j < 8; ++j)
        xb[t * DDIM + j * 64 + lane] = (short)(bpack(xv[j], 0.f) & 0xFFFFu);

#pragma unroll
    for (int o = 32; o > 0; o >>= 1) ss += __shfl_xor(ss, o);
    const float var = ss * (1.0f / 512.0f);
    const float coef = rsqrtf(var + 1e-6f) * rsqrtf(512.0f);

    __shared__ float ri[DDIM];
#pragma unroll
    for (int j = 0; j < 8; ++j) {
        const int d = j * 64 + lane;
        ri[d] = xv[j] * coef * rs[d];
    }
    __syncthreads();

    // logits: lane&31 -> expert, lane>>5 -> half of D; 4 partial accs break the chain
    const int e = lane & 31;
    const int half = lane >> 5;
    const int dbeg = half * 256;
    float l0 = 0.f, l1 = 0.f, l2 = 0.f, l3 = 0.f;
#pragma unroll 4
    for (int d = dbeg; d < dbeg + 256; d += 4) {
        l0 = fmaf(ri[d + 0], Wr[(d + 0) * NEXP + e], l0);
        l1 = fmaf(ri[d + 1], Wr[(d + 1) * NEXP + e], l1);
        l2 = fmaf(ri[d + 2], Wr[(d + 2) * NEXP + e], l2);
        l3 = fmaf(ri[d + 3], Wr[(d + 3) * NEXP + e], l3);
    }
    float lg = (l0 + l1) + (l2 + l3);
    lg += __shfl_xor(lg, 32);

    __shared__ float lgs[NEXP];
    if (lane < 32) lgs[lane] = lg;
    __syncthreads();

    if (lane == 0) {
        int i0 = 0; float m0 = lgs[0];
        for (int i = 1; i < NEXP; ++i) if (lgs[i] > m0) { m0 = lgs[i]; i0 = i; }
        int i1 = -1; float m1 = -1e30f;
        for (int i = 0; i < NEXP; ++i) if (i != i0 && lgs[i] > m1) { m1 = lgs[i]; i1 = i; }
        // softmax denom cancels against renorm: weights depend only on top-2 logits
        const float e1 = expf(m1 - m0);
        const float inv = 1.0f / (1.0f + e1);
        const float w0 = inv, w1 = e1 * inv;

        int p0 = atomicAdd(&cnt[i0], 1);
        alist[i0 * LTOK + p0] = t * 2;
        slist[i0 * LTOK + p0] = w0 * pes[i0];
        int p1 = atomicAdd(&cnt[i1], 1);
        alist[i1 * LTOK + p1] = t * 2 + 1;
        slist[i1 * LTOK + p1] = w1 * pes[i1];
    }
}

// grid (32, 32): blockIdx.x = 16-wide h tile, blockIdx.y = expert.
// 4 waves: wv = (khalf<<1) | gate. Wave's full B stream (its gate's 16 rows x 256 k
// = 16 KB) is loaded+packed into registers BEFORE the m-loop: 16 back-to-back
// float4 loads -> deep MLP; pack cost paid once per kernel.
// m-loop: 2 m-tiles of 16 token slots (E[Ne]=32). LDS reduction over K-halves.
__global__ __launch_bounds__(256, 4) void gates_kernel(
    const short* __restrict__ xb, const float* __restrict__ G,
    const int* __restrict__ cnt, const int* __restrict__ alist,
    short* __restrict__ act)
{
    const int e  = blockIdx.y;
    const int h0 = blockIdx.x * 16;
    const int Ne = cnt[e];
    if (Ne == 0) return;
    const int wv   = threadIdx.x >> 6;
    const int g    = wv & 1;    // gate index
    const int kh   = wv >> 1;   // K half
    const int lane = threadIdx.x & 63;
    const int n    = lane & 15;
    const int quad = lane >> 4;

    __shared__ float red[4][2][4][64];   // [wave][m-tile][reg][lane] = 8 KB

    const float* Grow = G + ((size_t)((e * 2 + g) * HDIM) + h0 + n) * DDIM + kh * 256;
    const short* xbh  = xb + kh * 256;
    const int* al = alist + e * LTOK;

    // ---- B preload: 8 ks-steps x short8 ----
    short8 Bf[8];
#pragma unroll
    for (int ks = 0; ks < 8; ++ks) {
        const int ko = ks * 32 + quad * 8;
        const floatx4 b0 = *(const floatx4*)(Grow + ko);
        const floatx4 b1 = *(const floatx4*)(Grow + ko + 4);
        union { short8 s; unsigned u[4]; } B;
        B.u[0] = bpack(b0.x, b0.y);
        B.u[1] = bpack(b0.z, b0.w);
        B.u[2] = bpack(b1.x, b1.y);
        B.u[3] = bpack(b1.z, b1.w);
        Bf[ks] = B.s;
    }

    for (int mb = 0; mb < Ne; mb += 32) {
        int arow[2];
#pragma unroll
        for (int i = 0; i < 2; ++i) {
            int s = mb + i * 16 + n;
            arow[i] = al[s < Ne ? s : Ne - 1] >> 1;   // token index
        }
        floatx4 acc[2] = {};

#pragma unroll
        for (int ks = 0; ks < 8; ++ks) {
            const int ko = ks * 32 + quad * 8;
#pragma unroll
            for (int i = 0; i < 2; ++i) {
                const short8 A = *(const short8*)(xbh + (size_t)arow[i] * DDIM + ko);
                acc[i] = __builtin_amdgcn_mfma_f32_16x16x32_bf16(A, Bf[ks], acc[i], 0, 0, 0);
            }
        }

#pragma unroll
        for (int i = 0; i < 2; ++i)
#pragma unroll
            for (int r = 0; r < 4; ++r)
                red[wv][i][r][lane] = acc[i][r];
        __syncthreads();

        // epilogue: wave handles m-tile (wv&1), regs {2u,2u+1} where u=wv>>1.
        // C/D: col = lane&15, row = quad*4 + r.
        {
            const int i = wv & 1;
            const int u = wv >> 1;
#pragma unroll
            for (int rr = 0; rr < 2; ++rr) {
                const int r = u * 2 + rr;
                const int s = mb + i * 16 + quad * 4 + r;
                if (s < Ne) {
                    const int a = al[s];
                    const float g0 = red[0][i][r][lane] + red[2][i][r][lane];
                    const float g1 = red[1][i][r][lane] + red[3][i][r][lane];
                    // gelu_tanh(g0) = g0 * sigmoid(2*u)
                    const float uu = 0.7978845608f * (g0 + 0.044715f * g0 * g0 * g0);
                    const float sg = 1.0f / (1.0f + __expf(-2.0f * uu));
                    const float v = g0 * sg * g1;
                    act[(size_t)a * HDIM + h0 + n] = (short)(bpack(v, 0.f) & 0xFFFFu);
                }
            }
        }
        __syncthreads();
    }
}

// grid (32, 32): blockIdx.x = 16-wide d tile, blockIdx.y = expert.
// 4 waves = K quarters (128 h each). Wave's B stream (its 128 h x 16 d column
// block of Wl) preloaded+packed into regs before the m-loop. Plain stores into
// per-assignment yb (scaled) -- no atomics; combine_kernel sums the two slots.
__global__ __launch_bounds__(256, 4) void linear_kernel(
    const short* __restrict__ act, const float* __restrict__ Wl,
    const int* __restrict__ cnt, const int* __restrict__ alist,
    const float* __restrict__ slist, float* __restrict__ yb)
{
    const int e  = blockIdx.y;
    const int d0 = blockIdx.x * 16;
    const int Ne = cnt[e];
    if (Ne == 0) return;
    const int wv   = threadIdx.x >> 6;
    const int lane = threadIdx.x & 63;
    const int n    = lane & 15;
    const int quad = lane >> 4;

    __shared__ float red[4][2][4][64];   // 8 KB

    const float* Wcol = Wl + (size_t)e * HDIM * DDIM + d0 + n;
    const int* al = alist + e * LTOK;
    const float* sl = slist + e * LTOK;

    // ---- B preload: 4 ks-steps x short8 (k = wv*128 + ks*32 + quad*8 + j) ----
    short8 Bf[4];
#pragma unroll
    for (int ks = 0; ks < 4; ++ks) {
        const int ko = wv * 128 + ks * 32 + quad * 8;
        float w[8];
#pragma unroll
        for (int j = 0; j < 8; ++j)
            w[j] = Wcol[(size_t)(ko + j) * DDIM];
        union { short8 s; unsigned u[4]; } B;
        B.u[0] = bpack(w[0], w[1]);
        B.u[1] = bpack(w[2], w[3]);
        B.u[2] = bpack(w[4], w[5]);
        B.u[3] = bpack(w[6], w[7]);
        Bf[ks] = B.s;
    }

    for (int mb = 0; mb < Ne; mb += 32) {
        int arow[2];
#pragma unroll
        for (int i = 0; i < 2; ++i) {
            int s = mb + i * 16 + n;
            arow[i] = al[s < Ne ? s : Ne - 1];   // assignment id = act row
        }
        floatx4 acc[2] = {};

#pragma unroll
        for (int ks = 0; ks < 4; ++ks) {
            const int ko = wv * 128 + ks * 32 + quad * 8;
#pragma unroll
            for (int i = 0; i < 2; ++i) {
                const short8 A = *(const short8*)(act + (size_t)arow[i] * HDIM + ko);
                acc[i] = __builtin_amdgcn_mfma_f32_16x16x32_bf16(A, Bf[ks], acc[i], 0, 0, 0);
            }
        }

#pragma unroll
        for (int i = 0; i < 2; ++i)
#pragma unroll
            for (int r = 0; r < 4; ++r)
                red[wv][i][r][lane] = acc[i][r];
        __syncthreads();

        {
            const int i = wv & 1;
            const int u = wv >> 1;
#pragma unroll
            for (int rr = 0; rr < 2; ++rr) {
                const int r = u * 2 + rr;
                const int s = mb + i * 16 + quad * 4 + r;
                if (s < Ne) {
                    const int a = al[s];
                    const float v = ((red[0][i][r][lane] + red[1][i][r][lane]) +
                                     (red[2][i][r][lane] + red[3][i][r][lane])) * sl[s];
                    yb[(size_t)a * DDIM + d0 + n] = v;
                }
            }
        }
        __syncthreads();
    }
}

// out[t][:] = yb[2t][:] + yb[2t+1][:]   (every assignment slot written exactly once)
__global__ __launch_bounds__(256) void combine_kernel(
    const float* __restrict__ yb, float* __restrict__ out)
{
    const int idx = blockIdx.x * 256 + threadIdx.x;   // 65536 float4s
    const int t = idx >> 7, c = idx & 127;
    const floatx4 a = ((const floatx4*)(yb + (size_t)(2 * t) * DDIM))[c];
    const floatx4 b = ((const floatx4*)(yb + (size_t)(2 * t + 1) * DDIM))[c];
    ((floatx4*)(out + (size_t)t * DDIM))[c] = a + b;
}

extern "C" void kernel_launch(void* const* d_in, const int* in_sizes, int n_in,
                              void* d_out, int out_size, void* d_ws, size_t ws_size,
                              hipStream_t stream)
{
    const float* x   = (const float*)d_in[0];
    const float* rs  = (const float*)d_in[1];
    const float* Wr  = (const float*)d_in[2];
    const float* G   = (const float*)d_in[3];
    const float* Wl  = (const float*)d_in[4];
    const float* pes = (const float*)d_in[5];
    float* out = (float*)d_out;

    char* ws = (char*)d_ws;
    int*   cnt   = (int*)(ws);
    int*   alist = (int*)(ws + 256);
    float* slist = (float*)(ws + 256 + 65536);
    short* xb    = (short*)(ws + 131328);
    short* act   = (short*)(ws + 655616);
    float* yb    = (float*)(ws + 1704192);

    hipMemsetAsync(cnt, 0, NEXP * sizeof(int), stream);

    router_kernel<<<dim3(LTOK), dim3(64), 0, stream>>>(x, rs, Wr, pes, cnt, alist, slist, xb);
    gates_kernel<<<dim3(32, NEXP), dim3(256), 0, stream>>>(xb, G, cnt, alist, act);
    linear_kernel<<<dim3(32, NEXP), dim3(256), 0, stream>>>(act, Wl, cnt, alist, slist, yb);
    combine_kernel<<<dim3(256), dim3(256), 0, stream>>>(yb, out);
}

// Round 5
// 158.280 us; speedup vs baseline: 1.0554x; 1.0554x over previous
//
#include <hip/hip_runtime.h>
#include <hip/hip_bf16.h>
#include <math.h>

#define LTOK 512
#define DDIM 512
#define NEXP 32
#define HDIM 512

typedef __attribute__((ext_vector_type(8))) short short8;
typedef __attribute__((ext_vector_type(4))) float floatx4;

// round-to-nearest-even fp32->bf16, packed pair: low16 = rne(a), high16 = rne(b)
__device__ __forceinline__ unsigned bpack(float a, float b) {
    unsigned ua = __float_as_uint(a), ub = __float_as_uint(b);
    ua += 0x7FFFu + ((ua >> 16) & 1u);
    ub += 0x7FFFu + ((ub >> 16) & 1u);
    return (ua >> 16) | (ub & 0xFFFF0000u);
}

// ws layout (bytes):
//   [0, 4K)        easgn: int[1024]   easgn[2t+k] = expert of token t's k-th pick
//   [4K, 8K)       wts:   float[1024] wts[2t+k]   = routing weight * per_expert_scale
//   [8K, +512K)    xb:    512x512 bf16 (x rounded to bf16)
//   [532480, +1M)  act:   1024x512 bf16 (slot-indexed activated gate output)
// total ~1.5 MB; no memsets required (dense tables, out zeroed by router)

__global__ __launch_bounds__(64) void router_kernel(
    const float* __restrict__ x, const float* __restrict__ rs,
    const float* __restrict__ Wr, const float* __restrict__ pes,
    int* __restrict__ easgn, float* __restrict__ wts,
    short* __restrict__ xb, float* __restrict__ out)
{
    const int t = blockIdx.x;
    const int lane = threadIdx.x;

    float xv[8];
    float ss = 0.f;
#pragma unroll
    for (int j = 0; j < 8; ++j) {
        xv[j] = x[t * DDIM + j * 64 + lane];
        ss += xv[j] * xv[j];
    }
    // emit bf16 copy of x for the expert GEMMs; zero this token's out row
#pragma unroll
    for (int j = 0; j < 8; ++j) {
        xb[t * DDIM + j * 64 + lane] = (short)(bpack(xv[j], 0.f) & 0xFFFFu);
        out[t * DDIM + j * 64 + lane] = 0.f;
    }

#pragma unroll
    for (int o = 32; o > 0; o >>= 1) ss += __shfl_xor(ss, o);
    const float var = ss * (1.0f / 512.0f);
    const float coef = rsqrtf(var + 1e-6f) * rsqrtf(512.0f);

    __shared__ float ri[DDIM];
#pragma unroll
    for (int j = 0; j < 8; ++j) {
        const int d = j * 64 + lane;
        ri[d] = xv[j] * coef * rs[d];
    }
    __syncthreads();

    // logits: lane&31 -> expert, lane>>5 -> half of D; 4 partial accs break the chain
    const int e = lane & 31;
    const int half = lane >> 5;
    const int dbeg = half * 256;
    float l0 = 0.f, l1 = 0.f, l2 = 0.f, l3 = 0.f;
#pragma unroll 4
    for (int d = dbeg; d < dbeg + 256; d += 4) {
        l0 = fmaf(ri[d + 0], Wr[(d + 0) * NEXP + e], l0);
        l1 = fmaf(ri[d + 1], Wr[(d + 1) * NEXP + e], l1);
        l2 = fmaf(ri[d + 2], Wr[(d + 2) * NEXP + e], l2);
        l3 = fmaf(ri[d + 3], Wr[(d + 3) * NEXP + e], l3);
    }
    float lg = (l0 + l1) + (l2 + l3);
    lg += __shfl_xor(lg, 32);

    __shared__ float lgs[NEXP];
    if (lane < 32) lgs[lane] = lg;
    __syncthreads();

    if (lane == 0) {
        int i0 = 0; float m0 = lgs[0];
        for (int i = 1; i < NEXP; ++i) if (lgs[i] > m0) { m0 = lgs[i]; i0 = i; }
        int i1 = -1; float m1 = -1e30f;
        for (int i = 0; i < NEXP; ++i) if (i != i0 && lgs[i] > m1) { m1 = lgs[i]; i1 = i; }
        // softmax denom cancels against renorm: weights depend only on top-2 logits
        const float e1 = expf(m1 - m0);
        const float inv = 1.0f / (1.0f + e1);
        easgn[2 * t]     = i0;
        easgn[2 * t + 1] = i1;
        wts[2 * t]     = inv * pes[i0];
        wts[2 * t + 1] = e1 * inv * pes[i1];
    }
}

// grid (32, 32): blockIdx.x = 16-wide h tile, blockIdx.y = expert.
// Self-selecting: block scans the dense easgn table (one int4/thread), compacts
// matching slot ids into LDS via LDS-atomic, then runs the MFMA body.
// 4 waves: wv = (khalf<<1) | gate; per-wave B stream preloaded to registers
// BEFORE the scan so the weight stream hides the scan latency.
__global__ __launch_bounds__(256, 4) void gates_kernel(
    const short* __restrict__ xb, const float* __restrict__ G,
    const int* __restrict__ easgn, short* __restrict__ act)
{
    const int e  = blockIdx.y;
    const int h0 = blockIdx.x * 16;
    const int tid = threadIdx.x;
    const int wv   = tid >> 6;
    const int g    = wv & 1;    // gate index
    const int kh   = wv >> 1;   // K half
    const int lane = tid & 63;
    const int n    = lane & 15;
    const int quad = lane >> 4;

    __shared__ int toks[2 * LTOK];
    __shared__ int lcnt;
    __shared__ float red[4][2][4][64];   // [wave][m-tile][reg][lane] = 8 KB

    const float* Grow = G + ((size_t)((e * 2 + g) * HDIM) + h0 + n) * DDIM + kh * 256;
    const short* xbh  = xb + kh * 256;

    // ---- B preload: 8 ks-steps x short8 (issues first; independent of scan) ----
    short8 Bf[8];
#pragma unroll
    for (int ks = 0; ks < 8; ++ks) {
        const int ko = ks * 32 + quad * 8;
        const floatx4 b0 = *(const floatx4*)(Grow + ko);
        const floatx4 b1 = *(const floatx4*)(Grow + ko + 4);
        union { short8 s; unsigned u[4]; } B;
        B.u[0] = bpack(b0.x, b0.y);
        B.u[1] = bpack(b0.z, b0.w);
        B.u[2] = bpack(b1.x, b1.y);
        B.u[3] = bpack(b1.z, b1.w);
        Bf[ks] = B.s;
    }

    // ---- self-select scan ----
    if (tid == 0) lcnt = 0;
    __syncthreads();
    {
        const int4 eg = ((const int4*)easgn)[tid];   // slots 4*tid .. 4*tid+3
        if (eg.x == e) { int p = atomicAdd(&lcnt, 1); toks[p] = 4 * tid; }
        if (eg.y == e) { int p = atomicAdd(&lcnt, 1); toks[p] = 4 * tid + 1; }
        if (eg.z == e) { int p = atomicAdd(&lcnt, 1); toks[p] = 4 * tid + 2; }
        if (eg.w == e) { int p = atomicAdd(&lcnt, 1); toks[p] = 4 * tid + 3; }
    }
    __syncthreads();
    const int Ne = lcnt;
    if (Ne == 0) return;

    for (int mb = 0; mb < Ne; mb += 32) {
        int arow[2];
#pragma unroll
        for (int i = 0; i < 2; ++i) {
            int s = mb + i * 16 + n;
            arow[i] = toks[s < Ne ? s : Ne - 1] >> 1;   // token index
        }
        floatx4 acc[2] = {};

#pragma unroll
        for (int ks = 0; ks < 8; ++ks) {
            const int ko = ks * 32 + quad * 8;
#pragma unroll
            for (int i = 0; i < 2; ++i) {
                const short8 A = *(const short8*)(xbh + (size_t)arow[i] * DDIM + ko);
                acc[i] = __builtin_amdgcn_mfma_f32_16x16x32_bf16(A, Bf[ks], acc[i], 0, 0, 0);
            }
        }

#pragma unroll
        for (int i = 0; i < 2; ++i)
#pragma unroll
            for (int r = 0; r < 4; ++r)
                red[wv][i][r][lane] = acc[i][r];
        __syncthreads();

        // epilogue: wave handles m-tile (wv&1), regs {2u,2u+1}, u=wv>>1.
        // C/D: col = lane&15, row = quad*4 + r.
        {
            const int i = wv & 1;
            const int u = wv >> 1;
#pragma unroll
            for (int rr = 0; rr < 2; ++rr) {
                const int r = u * 2 + rr;
                const int s = mb + i * 16 + quad * 4 + r;
                if (s < Ne) {
                    const int a = toks[s];   // slot id = act row
                    const float g0 = red[0][i][r][lane] + red[2][i][r][lane];
                    const float g1 = red[1][i][r][lane] + red[3][i][r][lane];
                    // gelu_tanh(g0) = g0 * sigmoid(2*u)
                    const float uu = 0.7978845608f * (g0 + 0.044715f * g0 * g0 * g0);
                    const float sg = 1.0f / (1.0f + __expf(-2.0f * uu));
                    const float v = g0 * sg * g1;
                    act[(size_t)a * HDIM + h0 + n] = (short)(bpack(v, 0.f) & 0xFFFFu);
                }
            }
        }
        __syncthreads();
    }
}

// grid (32, 32): blockIdx.x = 16-wide d tile, blockIdx.y = expert.
// Same self-select; 4 waves = K quarters; atomicAdd scaled result into out
// (zeroed by router).
__global__ __launch_bounds__(256, 4) void linear_kernel(
    const short* __restrict__ act, const float* __restrict__ Wl,
    const int* __restrict__ easgn, const float* __restrict__ wts,
    float* __restrict__ out)
{
    const int e  = blockIdx.y;
    const int d0 = blockIdx.x * 16;
    const int tid = threadIdx.x;
    const int wv   = tid >> 6;
    const int lane = tid & 63;
    const int n    = lane & 15;
    const int quad = lane >> 4;

    __shared__ int toks[2 * LTOK];
    __shared__ int lcnt;
    __shared__ float red[4][2][4][64];   // 8 KB

    const float* Wcol = Wl + (size_t)e * HDIM * DDIM + d0 + n;

    // ---- B preload: 4 ks-steps x short8 (k = wv*128 + ks*32 + quad*8 + j) ----
    short8 Bf[4];
#pragma unroll
    for (int ks = 0; ks < 4; ++ks) {
        const int ko = wv * 128 + ks * 32 + quad * 8;
        float w[8];
#pragma unroll
        for (int j = 0; j < 8; ++j)
            w[j] = Wcol[(size_t)(ko + j) * DDIM];
        union { short8 s; unsigned u[4]; } B;
        B.u[0] = bpack(w[0], w[1]);
        B.u[1] = bpack(w[2], w[3]);
        B.u[2] = bpack(w[4], w[5]);
        B.u[3] = bpack(w[6], w[7]);
        Bf[ks] = B.s;
    }

    // ---- self-select scan ----
    if (tid == 0) lcnt = 0;
    __syncthreads();
    {
        const int4 eg = ((const int4*)easgn)[tid];
        if (eg.x == e) { int p = atomicAdd(&lcnt, 1); toks[p] = 4 * tid; }
        if (eg.y == e) { int p = atomicAdd(&lcnt, 1); toks[p] = 4 * tid + 1; }
        if (eg.z == e) { int p = atomicAdd(&lcnt, 1); toks[p] = 4 * tid + 2; }
        if (eg.w == e) { int p = atomicAdd(&lcnt, 1); toks[p] = 4 * tid + 3; }
    }
    __syncthreads();
    const int Ne = lcnt;
    if (Ne == 0) return;

    for (int mb = 0; mb < Ne; mb += 32) {
        int arow[2];
#pragma unroll
        for (int i = 0; i < 2; ++i) {
            int s = mb + i * 16 + n;
            arow[i] = toks[s < Ne ? s : Ne - 1];   // slot id = act row
        }
        floatx4 acc[2] = {};

#pragma unroll
        for (int ks = 0; ks < 4; ++ks) {
            const int ko = wv * 128 + ks * 32 + quad * 8;
#pragma unroll
            for (int i = 0; i < 2; ++i) {
                const short8 A = *(const short8*)(act + (size_t)arow[i] * HDIM + ko);
                acc[i] = __builtin_amdgcn_mfma_f32_16x16x32_bf16(A, Bf[ks], acc[i], 0, 0, 0);
            }
        }

#pragma unroll
        for (int i = 0; i < 2; ++i)
#pragma unroll
            for (int r = 0; r < 4; ++r)
                red[wv][i][r][lane] = acc[i][r];
        __syncthreads();

        {
            const int i = wv & 1;
            const int u = wv >> 1;
#pragma unroll
            for (int rr = 0; rr < 2; ++rr) {
                const int r = u * 2 + rr;
                const int s = mb + i * 16 + quad * 4 + r;
                if (s < Ne) {
                    const int slot = toks[s];
                    const float v = ((red[0][i][r][lane] + red[1][i][r][lane]) +
                                     (red[2][i][r][lane] + red[3][i][r][lane])) * wts[slot];
                    atomicAdd(&out[(size_t)(slot >> 1) * DDIM + d0 + n], v);
                }
            }
        }
        __syncthreads();
    }
}

extern "C" void kernel_launch(void* const* d_in, const int* in_sizes, int n_in,
                              void* d_out, int out_size, void* d_ws, size_t ws_size,
                              hipStream_t stream)
{
    const float* x   = (const float*)d_in[0];
    const float* rs  = (const float*)d_in[1];
    const float* Wr  = (const float*)d_in[2];
    const float* G   = (const float*)d_in[3];
    const float* Wl  = (const float*)d_in[4];
    const float* pes = (const float*)d_in[5];
    float* out = (float*)d_out;

    char* ws = (char*)d_ws;
    int*   easgn = (int*)(ws);
    float* wts   = (float*)(ws + 4096);
    short* xb    = (short*)(ws + 8192);
    short* act   = (short*)(ws + 532480);

    router_kernel<<<dim3(LTOK), dim3(64), 0, stream>>>(x, rs, Wr, pes, easgn, wts, xb, out);
    gates_kernel<<<dim3(32, NEXP), dim3(256), 0, stream>>>(xb, G, easgn, act);
    linear_kernel<<<dim3(32, NEXP), dim3(256), 0, stream>>>(act, Wl, easgn, wts, out);
}